// Round 7
// baseline (110.430 us; speedup 1.0000x reference)
//
#include <hip/hip_runtime.h>
#include <math.h>

// ---------- constants (normalization folded per the reference) ----------
#define SQ15f      3.8729833462074170f   // sqrt(15)
#define C2_XZ      1.7320508075688772f   // sqrt(3)
#define C2_ZX      0.8660254037844386f   // sqrt(3)/2
#define C3_A       0.4082482904638631f   // 1/sqrt(6)
#define C3_B       0.6123724356957945f   // sqrt(24)/8
#define EMB_SCALE  2.8234622000789103f   // sqrt(10)/1.12

typedef float v2f __attribute__((ext_vector_type(2)));
typedef float v4f __attribute__((ext_vector_type(4)));

// Per-wave scratch, no barriers. Chunk = 32 edges.
//   emb: logical p in [0,320)  -> scr[p + (p>>4)]          (<= 340)
//   sh : logical p in [0,512)  -> scr[340 + p + (p>>4)]    (<= 883)
// pad-every-16 makes the stride-4 cooperative reads bank-conflict-free;
// writes are stride 10/17 -> <=2-way. Intra-wave DS ops are in-order, so
// write->read->overwrite across chunks needs no sync.
#define WSCR 896

__global__ __launch_bounds__(256)
void fused_kernel(const float* __restrict__ pos,
                  const float* __restrict__ qpos,
                  const float* __restrict__ feat,
                  const int*   __restrict__ esrc,
                  const int*   __restrict__ edst,
                  float* __restrict__ out,
                  int E, int nblk_edge, int n2feat,
                  unsigned long long OFF_SRC, unsigned long long OFF_DST,
                  unsigned long long OFF_EMB, unsigned long long OFF_SH,
                  unsigned long long OFF_LEN) {
    const int tid = threadIdx.x;
    const int blk = blockIdx.x;

    if (blk >= nblk_edge) {                 // ---- feature passthrough blocks ----
        int i = (blk - nblk_edge) * 256 + tid;
        if (i == 0) { out[0] = 10.0f; out[1] = 1000.0f; }   // Nt, Ny
        if (i < n2feat) {
            v2f v = __builtin_nontemporal_load(((const v2f*)feat) + i);
            __builtin_nontemporal_store(v, ((v2f*)(out + 2)) + i);
        }
        return;
    }

    __shared__ float scr_all[4 * WSCR];
    const int lane = tid & 63;
    const int wv   = tid >> 6;
    float* wb = &scr_all[wv * WSCR];

    const int base = blk * 256;
    const int nb   = min(256, E - base);
    const int e    = base + tid;

    float em[10], sh[16], len;
    int s = 0, d = 0;

    if (tid < nb) {
        s = __builtin_nontemporal_load(esrc + e);
        d = __builtin_nontemporal_load(edst + e);

        float vx = qpos[3 * s + 0] - pos[3 * d + 0];
        float vy = qpos[3 * s + 1] - pos[3 * d + 1];
        float vz = qpos[3 * s + 2] - pos[3 * d + 2];

        float ss  = vx * vx + vy * vy + vz * vz;
        len = sqrtf(ss + 1e-8f);

        float n   = sqrtf(ss);
        float inv = 1.0f / fmaxf(n, 1e-12f);
        float x = vx * inv, y = vy * inv, z = vz * inv;

        float x2 = x * x, y2 = y * y, z2 = z * z;
        float x2z2 = x2 + z2;

        float s20 = SQ15f * x * z;
        float s24 = 0.5f * SQ15f * (z2 - x2);
        float q   = 4.0f * y2 - x2z2;

        sh[0] = 1.0f;
        sh[1] = x;  sh[2] = y;  sh[3] = z;
        sh[4] = C2_XZ * x * z;
        sh[5] = C2_XZ * x * y;
        sh[6] = y2 - 0.5f * x2z2;
        sh[7] = C2_XZ * y * z;
        sh[8] = C2_ZX * (z2 - x2);
        sh[9]  = C3_A * (s20 * z + s24 * x);
        sh[10] = s20 * y;
        sh[11] = C3_B * q * x;
        sh[12] = 0.5f * y * (2.0f * y2 - 3.0f * x2z2);
        sh[13] = C3_B * z * q;
        sh[14] = s24 * y;
        sh[15] = C3_A * (s24 * z - s20 * x);

        float t = (0.2f - len) * 5.5f;
        float cut;
        if (t <= 0.0f)      cut = 1.0f;
        else if (t >= 1.0f) cut = 0.0f;
        else {
            float t2 = t * t;
            float t4 = t2 * t2;
            cut = 1.0f - (5.0f * t4 - 4.0f * t4 * t);
        }
        float cs = cut * EMB_SCALE;

#pragma unroll
        for (int i = 0; i < 10; ++i) {
            float m  = (9.0f + 8.0f * (float)i) * (1.0f / 81.0f);
            float dd = (len - m) * 9.0f;
            em[i] = __expf(-dd * dd) * cs;
        }

        __builtin_nontemporal_store((float)s, out + OFF_SRC + e);
        __builtin_nontemporal_store((float)d, out + OFF_DST + e);
        __builtin_nontemporal_store(len,      out + OFF_LEN + e);
    }

    if (nb == 256) {
        const int r = lane & 31;
#pragma unroll
        for (int k = 0; k < 2; ++k) {
            // ---- stage this chunk's 32 rows (half the wave writes) ----
            if ((lane >> 5) == k) {
#pragma unroll
                for (int j = 0; j < 10; ++j) { int p = r * 10 + j; wb[p + (p >> 4)] = em[j]; }
#pragma unroll
                for (int c = 0; c < 16; ++c) { wb[340 + r * 17 + c] = sh[c]; }
            }
            // ---- cooperative chunk stores (all 64 lanes) ----
            const unsigned long long cb = (unsigned long long)base + wv * 64 + k * 32;
            float* ge = out + OFF_EMB + 10ULL * cb;   // 320-float span, start ≡2 mod 4
            float* gs = out + OFF_SH  + 16ULL * cb;   // 512-float span, start ≡2 mod 4

            if (lane == 0) { v2f h = { wb[0], wb[1] };
                             __builtin_nontemporal_store(h, (v2f*)ge); }
            if (lane == 1) { v2f t = { wb[318 + (318 >> 4)], wb[319 + (319 >> 4)] };
                             __builtin_nontemporal_store(t, (v2f*)(ge + 318)); }
#pragma unroll
            for (int it = 0; it < 2; ++it) {
                int i = it * 64 + lane;
                if (i < 79) {
                    int p0 = 2 + 4 * i;
                    v4f v = { wb[p0     + (p0 >> 4)],
                              wb[p0 + 1 + ((p0 + 1) >> 4)],
                              wb[p0 + 2 + ((p0 + 2) >> 4)],
                              wb[p0 + 3 + ((p0 + 3) >> 4)] };
                    __builtin_nontemporal_store(v, (v4f*)(ge + p0));
                }
            }

            if (lane == 2) { v2f h = { wb[340 + 0], wb[340 + 1] };
                             __builtin_nontemporal_store(h, (v2f*)gs); }
            if (lane == 3) { v2f t = { wb[340 + 510 + (510 >> 4)], wb[340 + 511 + (511 >> 4)] };
                             __builtin_nontemporal_store(t, (v2f*)(gs + 510)); }
#pragma unroll
            for (int it = 0; it < 2; ++it) {
                int i = it * 64 + lane;
                if (i < 127) {
                    int p0 = 2 + 4 * i;
                    v4f v = { wb[340 + p0     + (p0 >> 4)],
                              wb[340 + p0 + 1 + ((p0 + 1) >> 4)],
                              wb[340 + p0 + 2 + ((p0 + 2) >> 4)],
                              wb[340 + p0 + 3 + ((p0 + 3) >> 4)] };
                    __builtin_nontemporal_store(v, (v4f*)(gs + p0));
                }
            }
        }
    } else if (tid < nb) {
        // ---- tail block: direct scalar stores from registers ----
        float* ge = out + OFF_EMB + 10ULL * (unsigned long long)e;
        float* gs = out + OFF_SH  + 16ULL * (unsigned long long)e;
#pragma unroll
        for (int j = 0; j < 10; ++j) __builtin_nontemporal_store(em[j], ge + j);
#pragma unroll
        for (int c = 0; c < 16; ++c) __builtin_nontemporal_store(sh[c], gs + c);
    }
}

extern "C" void kernel_launch(void* const* d_in, const int* in_sizes, int n_in,
                              void* d_out, int out_size, void* d_ws, size_t ws_size,
                              hipStream_t stream) {
    const float* pos  = (const float*)d_in[0];
    const float* qpos = (const float*)d_in[1];
    const float* feat = (const float*)d_in[2];
    const int*   esrc = (const int*)d_in[3];
    const int*   edst = (const int*)d_in[4];
    float* out = (float*)d_out;

    const int Ftot = in_sizes[2];   // 320000
    const int E    = in_sizes[3];   // 3000000

    const unsigned long long OFF_FEAT = 2;
    const unsigned long long OFF_SRC  = OFF_FEAT + (unsigned long long)Ftot;
    const unsigned long long OFF_DST  = OFF_SRC + (unsigned long long)E;
    const unsigned long long OFF_EMB  = OFF_DST + (unsigned long long)E;
    const unsigned long long OFF_SH   = OFF_EMB + 10ULL * E;
    const unsigned long long OFF_LEN  = OFF_SH  + 16ULL * E;

    const int n2feat    = Ftot / 2;
    const int nblk_edge = (E + 255) / 256;
    const int nblk_feat = (n2feat + 255) / 256;

    fused_kernel<<<nblk_edge + nblk_feat, 256, 0, stream>>>(
        pos, qpos, feat, esrc, edst, out,
        E, nblk_edge, n2feat, OFF_SRC, OFF_DST, OFF_EMB, OFF_SH, OFF_LEN);
}